// Round 16
// baseline (234.911 us; speedup 1.0000x reference)
//
#include <hip/hip_runtime.h>
#include <hip/hip_bf16.h>

// M=2 branches, K=3 diffusion, N=64, I=1, H=64, B=8, T=12

typedef __attribute__((ext_vector_type(8))) short short8;   // 8 bf16 (4 VGPRs)
typedef __attribute__((ext_vector_type(4))) float f32x4;    // 4 fp32

__device__ __forceinline__ short bf16_cvt(float f) {       // RNE, 1-2 ops
    __hip_bfloat16 h = __float2bfloat16(f);
    return __builtin_bit_cast(short, h);
}
__device__ __forceinline__ float bf16_tof(short s) {
    union { unsigned u; float f; } v; v.u = ((unsigned)s) << 16;
    return v.f;
}

// ---------------- prep: pack W, G^T, Whh into MFMA fragment order ----------
// Wf [layer][br][d][ht][kk][lane][8] : 147456/plane
// Gf [br][et][kk][lane][8]           : 24576/plane
// Whf[br][kt][gg][w][lane][8]        : 32768/plane  (B[k][gate] of WhhT)
__global__ __launch_bounds__(256) void k_prep(
    const float* __restrict__ G, const float* __restrict__ W0,
    const float* __restrict__ W1, const float* __restrict__ whh,
    short* __restrict__ Wfhi, short* __restrict__ Wflo,
    short* __restrict__ Gfhi, short* __restrict__ Gflo,
    short* __restrict__ Whfhi, short* __restrict__ Whflo)
{
    int idx = blockIdx.x * 256 + threadIdx.x;
    float v; short *dh, *dl; int didx;
    if (idx < 147456) {
        int j = idx & 7, lane = (idx >> 3) & 63, kk = (idx >> 9) % 6;
        int t2 = idx / 3072;
        int ht = t2 & 3; t2 >>= 2;
        int d = t2 % 3; t2 /= 3;
        int br = t2 & 1, layer = t2 >> 1;
        int k = kk * 32 + ((lane >> 4) << 3) + j;
        int o = k >> 6, l = k & 63, h = ht * 16 + (lane & 15);
        const float* Wp = layer ? W1 : W0;
        v = Wp[((size_t)br * 576 + (o * 3 + d) * 64 + l) * 64 + h];
        dh = Wfhi; dl = Wflo; didx = idx;
    } else if (idx < 172032) {
        int i2 = idx - 147456;
        int j = i2 & 7, lane = (i2 >> 3) & 63, kk = (i2 >> 9) % 6;
        int t2 = i2 / 3072;
        int et = t2 & 3, br = t2 >> 2;
        int k = kk * 32 + ((lane >> 4) << 3) + j;
        int d = k >> 6, c = k & 63, e = et * 16 + (lane & 15);
        v = G[(((size_t)br * 3 + d) * 64 + c) * 64 + e];
        dh = Gfhi; dl = Gflo; didx = i2;
    } else {
        int i3 = idx - 172032;
        int j = i3 & 7, lane = (i3 >> 3) & 63;
        int w = (i3 >> 9) & 3, gg = (i3 >> 11) & 3;
        int kt = (i3 >> 13) & 1, br = (i3 >> 14) & 1;
        int gate = gg * 64 + w * 16 + (lane & 15);
        int k = kt * 32 + ((lane >> 4) << 3) + j;
        v = whh[((size_t)br * 256 + gate) * 64 + k];
        dh = Whfhi; dl = Whflo; didx = i3;
    }
    short hi = bf16_cvt(v);
    dh[didx] = hi;
    dl[didx] = bf16_cvt(v - bf16_tof(hi));
}

// ---------------- LSTM v5: Bh register-stationary, Bl streamed from L2 -----
// Round-15 analysis: (256,3) allocator uses ~168 total regs -> 3 waves/SIMD,
// ~30% stall. Freeing the Bl half of the weight block (32 VGPR) brings the
// live set to ~111 <= 128 -> 4 waves/SIMD fills the stall. Bl is re-loaded
// per step from the 64KB packed table (L2-hot, all blocks share it; ~5 TB/s
// of 35). asm-opaque pointer per step defeats cross-step CSE re-hoisting.
// Tripwires: WRITE_SIZE must stay 16 MB (spill), FETCH_SIZE ~2 MB (L2-hot).
__global__ __launch_bounds__(256, 4) void k_lstm(
    const float* __restrict__ x, const short* __restrict__ Whfhi,
    const short* __restrict__ Whflo, const float* __restrict__ wih,
    const float* __restrict__ bih, const float* __restrict__ bhh,
    short* __restrict__ Xhi, short* __restrict__ Xlo)
{
    __shared__ short hbuf[2][2][16][64];   // [dbuf][plane][seq][hid^swz] 8 KB
    const int tid = threadIdx.x;
    const int lane = tid & 63;
    const int w = __builtin_amdgcn_readfirstlane(tid >> 6);   // gate slice 0..3
    const int q = lane >> 4, r16 = lane & 15;
    const int br = blockIdx.y;
    const int bx = blockIdx.x;
    const int dg = bx & 3, o = (bx >> 2) & 63, b = bx >> 8;

    // hi-plane weight fragments register-stationary (32 VGPR)
    short8 Bh[2][4];
    const short* wbl0 = Whflo + (size_t)br * 16384 + (size_t)w * 512 + lane * 8;
    {
        const short* wbh = Whfhi + (size_t)br * 16384;
#pragma unroll
        for (int kt = 0; kt < 2; ++kt)
#pragma unroll
            for (int gg = 0; gg < 4; ++gg) {
                const int bidx = (((kt * 4 + gg) * 4 + w) * 64 + lane) * 8;
                Bh[kt][gg] = *(const short8*)(wbh + bidx);
            }
    }

    float wihv[4], biasv[4];
#pragma unroll
    for (int gg = 0; gg < 4; ++gg) {
        const int gate = gg * 64 + w * 16 + r16;
        wihv[gg] = wih[br * 256 + gate];
        biasv[gg] = bih[br * 256 + gate] + bhh[br * 256 + gate];
    }

    float cst[4] = {0.f, 0.f, 0.f, 0.f};
    const float* xb = x + (size_t)b * 12 * 4096 + o * 64 + dg * 16;
    const size_t hob = ((size_t)(br * 8 + b) * 64 + o) * 4096 + dg * 1024;
    const int hid = w * 16 + r16;

    const float L2E = 1.442695041f, L2E2 = 2.885390082f;

    float4 nx = *(const float4*)(xb + q * 4);   // prefetch t=0

    for (int t = 0; t < 12; ++t) {
        // per-step opaque copy of the Bl base: loads stay in-loop (no CSE
        // hoisting into 32 live registers across all 12 steps)
        const short* blp = wbl0;
        asm volatile("" : "+v"(blp));

        float4 xv = nx;
        if (t < 11)
            nx = *(const float4*)(xb + (size_t)(t + 1) * 4096 + q * 4);
        float xm[4] = {xv.x, xv.y, xv.z, xv.w};
        f32x4 acc[4];   // [gg]
#pragma unroll
        for (int r = 0; r < 4; ++r)
#pragma unroll
            for (int gg = 0; gg < 4; ++gg)
                acc[gg][r] = fmaf(xm[r], wihv[gg], biasv[gg]);

        if (t > 0) {
            const short* hb0 = &hbuf[t & 1][0][0][0];
#pragma unroll
            for (int kt = 0; kt < 2; ++kt) {
                // stream this kt's lo-plane fragments (L2-hot, 4x16B/lane)
                short8 Bl[4];
#pragma unroll
                for (int gg = 0; gg < 4; ++gg)
                    Bl[gg] = *(const short8*)(blp + (kt * 4 + gg) * 2048);
                const int col = (kt * 32 + q * 8) ^ ((r16 & 7) << 3);
                short8 Ah = *(const short8*)&hb0[r16 * 64 + col];
                short8 Al = *(const short8*)&hb0[1024 + r16 * 64 + col];
#pragma unroll
                for (int gg = 0; gg < 4; ++gg) {
                    acc[gg] = __builtin_amdgcn_mfma_f32_16x16x32_bf16(
                        Ah, Bh[kt][gg], acc[gg], 0, 0, 0);
                    acc[gg] = __builtin_amdgcn_mfma_f32_16x16x32_bf16(
                        Ah, Bl[gg], acc[gg], 0, 0, 0);
                    acc[gg] = __builtin_amdgcn_mfma_f32_16x16x32_bf16(
                        Al, Bh[kt][gg], acc[gg], 0, 0, 0);
                }
            }
        }
        // activations, torch order i,f,g,o. Fused products share one rcp.
        float hv_[4];
#pragma unroll
        for (int r = 0; r < 4; ++r) {
            float ei = __builtin_amdgcn_exp2f(acc[0][r] * -L2E);
            float Eg = __builtin_amdgcn_exp2f(acc[2][r] * L2E2);
            float ef = __builtin_amdgcn_exp2f(acc[1][r] * -L2E);
            float igt = (Eg - 1.f) *
                        __builtin_amdgcn_rcpf((1.f + ei) * (Eg + 1.f));
            float fg = __builtin_amdgcn_rcpf(1.f + ef);
            float c = fmaf(fg, cst[r], igt);
            cst[r] = c;
            float eo = __builtin_amdgcn_exp2f(acc[3][r] * -L2E);
            float Ec = __builtin_amdgcn_exp2f(c * L2E2);
            hv_[r] = (Ec - 1.f) *
                     __builtin_amdgcn_rcpf((1.f + eo) * (Ec + 1.f));
        }
        if (t == 11) {
#pragma unroll
            for (int r = 0; r < 4; ++r) {
                int seq = q * 4 + r;
                short hi = bf16_cvt(hv_[r]);
                Xhi[hob + seq * 64 + hid] = hi;
                Xlo[hob + seq * 64 + hid] = bf16_cvt(hv_[r] - bf16_tof(hi));
            }
        } else {
            short* hw0 = &hbuf[(t + 1) & 1][0][0][0];
#pragma unroll
            for (int r = 0; r < 4; ++r) {
                int seq = q * 4 + r;
                int col = hid ^ ((seq & 7) << 3);
                short hi = bf16_cvt(hv_[r]);
                hw0[seq * 64 + col] = hi;
                hw0[1024 + seq * 64 + col] = bf16_cvt(hv_[r] - bf16_tof(hi));
            }
            __syncthreads();   // single barrier per step (dbuf)
        }
    }
}

// ---------------- T1 v3.1: thread owns 8 cl x 8 m, X prefetched ------------
// T1[br][o][b][m][cl] = sum_n G[br][o][n][m] * X[br][b][n][cl]
__global__ __launch_bounds__(256, 3) void k_t1(
    const short* __restrict__ Xhi, const short* __restrict__ Xlo,
    const float* __restrict__ G,
    short* __restrict__ T1hi, short* __restrict__ T1lo)
{
    const int o = blockIdx.y >> 3, b = blockIdx.y & 7;
    const int br = blockIdx.z >> 3, m0 = (blockIdx.z & 7) * 8;
    const int cl0 = blockIdx.x * 2048 + threadIdx.x * 8;
    const size_t xb = (size_t)(br * 8 + b) * 262144 + cl0;
    const float* gp = G + (size_t)(br * 3 + o) * 4096 + m0;

    float acc[8][8];   // [mm][c]
#pragma unroll
    for (int mm = 0; mm < 8; ++mm)
#pragma unroll
        for (int c = 0; c < 8; ++c) acc[mm][c] = 0.f;

    short8 nxh = *(const short8*)(Xhi + xb);     // prefetch n=0
    short8 nxl = *(const short8*)(Xlo + xb);

#pragma unroll 2
    for (int n = 0; n < 64; ++n) {
        short8 xh = nxh, xl = nxl;
        if (n < 63) {   // issue n+1's loads; latency hides under n's fma
            nxh = *(const short8*)(Xhi + xb + (size_t)(n + 1) * 4096);
            nxl = *(const short8*)(Xlo + xb + (size_t)(n + 1) * 4096);
        }
        float xf[8];
#pragma unroll
        for (int c = 0; c < 8; ++c)
            xf[c] = bf16_tof(xh[c]) + bf16_tof(xl[c]);
        const float* gr = gp + n * 64;
#pragma unroll
        for (int mm = 0; mm < 8; ++mm) {
            float g = gr[mm];
#pragma unroll
            for (int c = 0; c < 8; ++c)
                acc[mm][c] = fmaf(xf[c], g, acc[mm][c]);
        }
    }
    const size_t tb = ((size_t)(br * 3 + o) * 8 + b) * 262144 + cl0;
#pragma unroll
    for (int mm = 0; mm < 8; ++mm) {
        short8 h8, l8;
#pragma unroll
        for (int c = 0; c < 8; ++c) {
            float f = acc[mm][c];
            short hi = bf16_cvt(f);
            h8[c] = hi;
            l8[c] = bf16_cvt(f - bf16_tof(hi));
        }
        *(short8*)(T1hi + tb + (size_t)(m0 + mm) * 4096) = h8;
        *(short8*)(T1lo + tb + (size_t)(m0 + mm) * 4096) = l8;
    }
}

// ---------------- T2 + FC (MFMA), LDS-staged T1, wave-split W --------------
// Per (br,b,m): U[d][c][h] = sum_{o,l} T1[o][c][l] W[(o,d)l][h]   (phase 1)
//              out[e][h]  = bias[h] + sum_{d,c} G[d][c][e] U[d][c][h] (ph 2)
// U layout: round-8 72-pad. LDS 55296 B.
__global__ __launch_bounds__(256, 3) void k_t2fc(
    const short* __restrict__ T1hi, const short* __restrict__ T1lo,
    const short* __restrict__ Wfhi, const short* __restrict__ Wflo,
    const short* __restrict__ Gfhi, const short* __restrict__ Gflo,
    const float* __restrict__ bias, const float* __restrict__ fcW,
    const float* __restrict__ fcb,
    short* __restrict__ Yhi, short* __restrict__ Ylo,
    float* __restrict__ yws, int last)
{
    // region reuse: stage T1 [6][4096] (24576 sh) -> U [2][3][64][72] (27648)
    __shared__ __align__(16) short lds[27648];
    const int tid = threadIdx.x, lane = tid & 63;
    const int r16 = lane & 15, q = lane >> 4;
    const int w = __builtin_amdgcn_readfirstlane(tid >> 6);
    const int m = blockIdx.x, b = blockIdx.y, br = blockIdx.z;

    // ---- stage T1 slice (3 o x 2 plane x 4096) into LDS, XOR-swizzled ----
    const size_t t1b = (((size_t)br * 24 + b) * 64 + m) * 4096;
#pragma unroll
    for (int it = 0; it < 12; ++it) {
        int flat = it * 2048 + tid * 8;
        int p2 = flat >> 12;            // o*2 + plane
        int li = flat & 4095;           // c*64 + l
        int c = li >> 6, l = li & 63;
        const short* src = ((p2 & 1) ? T1lo : T1hi) + t1b +
                           (size_t)(p2 >> 1) * 2097152 + li;
        int dst = p2 * 4096 + c * 64 + (l ^ ((c & 7) << 3));
        *(short8*)&lds[dst] = *(const short8*)src;
    }
    __syncthreads();

    // ---- phase 1: U = T1 @ W. Wave w owns combos {w*3..w*3+2} (d*4+ht),
    //      all 4 c-tiles. W-frag loads: 36/wave (no cross-wave redundancy).
    f32x4 acc1[3][4];   // [i][ct]
#pragma unroll
    for (int i = 0; i < 3; ++i)
#pragma unroll
        for (int ct = 0; ct < 4; ++ct)
#pragma unroll
            for (int r = 0; r < 4; ++r) acc1[i][ct][r] = 0.f;

#pragma unroll
    for (int kk = 0; kk < 6; ++kk) {
        const int o = kk >> 1;
        short8 Wh[3], Wl[3];
#pragma unroll
        for (int i = 0; i < 3; ++i) {
            const int combo = w * 3 + i;          // d*4 + ht
            const int d = combo >> 2, ht = combo & 3;
            const int widx = ((((br * 3 + d) * 4 + ht) * 6 + kk) << 9) + lane * 8;
            Wh[i] = *(const short8*)(Wfhi + widx);
            Wl[i] = *(const short8*)(Wflo + widx);
        }
        short8 Ah[4], Al[4];
#pragma unroll
        for (int ct = 0; ct < 4; ++ct) {
            const int c = ct * 16 + r16;
            const int lbase = ((kk & 1) * 32 + q * 8) ^ ((r16 & 7) << 3);
            Ah[ct] = *(const short8*)&lds[(o * 2 + 0) * 4096 + c * 64 + lbase];
            Al[ct] = *(const short8*)&lds[(o * 2 + 1) * 4096 + c * 64 + lbase];
        }
#pragma unroll
        for (int i = 0; i < 3; ++i)
#pragma unroll
            for (int ct = 0; ct < 4; ++ct) {
                acc1[i][ct] = __builtin_amdgcn_mfma_f32_16x16x32_bf16(
                    Ah[ct], Wh[i], acc1[i][ct], 0, 0, 0);
                acc1[i][ct] = __builtin_amdgcn_mfma_f32_16x16x32_bf16(
                    Ah[ct], Wl[i], acc1[i][ct], 0, 0, 0);
                acc1[i][ct] = __builtin_amdgcn_mfma_f32_16x16x32_bf16(
                    Al[ct], Wh[i], acc1[i][ct], 0, 0, 0);
            }
    }
    __syncthreads();   // T1-LDS reads done; region becomes U

    short* u0 = lds;
    short* u1 = lds + 13824;   // 3*64*72
#pragma unroll
    for (int i = 0; i < 3; ++i) {
        const int combo = w * 3 + i;
        const int d = combo >> 2, ht = combo & 3;
        const int h = ht * 16 + r16;
#pragma unroll
        for (int ct = 0; ct < 4; ++ct)
#pragma unroll
            for (int r = 0; r < 4; ++r) {
                float f = acc1[i][ct][r];
                int c = ct * 16 + q * 4 + r;
                int ui = (d * 64 + h) * 72 + c;
                short hi = bf16_cvt(f);
                u0[ui] = hi;
                u1[ui] = bf16_cvt(f - bf16_tof(hi));
            }
    }
    __syncthreads();

    // ---- phase 2: out = G^T @ U + bias (wave w owns e-tile w)
    f32x4 acc2[4];
#pragma unroll
    for (int ht = 0; ht < 4; ++ht) {
        float bb = bias[br * 64 + ht * 16 + r16];
#pragma unroll
        for (int r = 0; r < 4; ++r) acc2[ht][r] = bb;
    }
#pragma unroll
    for (int kk = 0; kk < 6; ++kk) {
        const int gi = (((br * 4 + w) * 6 + kk) << 9) + lane * 8;
        short8 A2h = *(const short8*)(Gfhi + gi);
        short8 A2l = *(const short8*)(Gflo + gi);
        const int d = kk >> 1, cb = (kk & 1) * 32 + q * 8;
#pragma unroll
        for (int ht = 0; ht < 4; ++ht) {
            const int bi = (d * 64 + ht * 16 + r16) * 72 + cb;
            short8 B2h = *(const short8*)(u0 + bi);
            short8 B2l = *(const short8*)(u1 + bi);
            acc2[ht] = __builtin_amdgcn_mfma_f32_16x16x32_bf16(
                A2h, B2h, acc2[ht], 0, 0, 0);
            acc2[ht] = __builtin_amdgcn_mfma_f32_16x16x32_bf16(
                A2h, B2l, acc2[ht], 0, 0, 0);
            acc2[ht] = __builtin_amdgcn_mfma_f32_16x16x32_bf16(
                A2l, B2h, acc2[ht], 0, 0, 0);
        }
    }

    if (!last) {
        __syncthreads();
        float* ldsO = (float*)lds;   // 16 KB
#pragma unroll
        for (int ht = 0; ht < 4; ++ht)
#pragma unroll
            for (int r = 0; r < 4; ++r)
                ldsO[(w * 16 + q * 4 + r) * 64 + ht * 16 + r16] = acc2[ht][r];
        __syncthreads();
        const size_t yb = ((size_t)(br * 8 + b) * 64 + m) * 4096;
        const int i0 = tid * 16;
#pragma unroll
        for (int half = 0; half < 2; ++half) {
            short8 h8, l8;
#pragma unroll
            for (int ii = 0; ii < 8; ++ii) {
                float f = ldsO[i0 + half * 8 + ii];
                short hi = bf16_cvt(f);
                h8[ii] = hi;
                l8[ii] = bf16_cvt(f - bf16_tof(hi));
            }
            *(short8*)(Yhi + yb + i0 + half * 8) = h8;
            *(short8*)(Ylo + yb + i0 + half * 8) = l8;
        }
    } else {
        float p[4];
#pragma unroll
        for (int r = 0; r < 4; ++r) {
            p[r] = 0.f;
#pragma unroll
            for (int ht = 0; ht < 4; ++ht)
                p[r] += acc2[ht][r] * fcW[br * 64 + ht * 16 + r16];
        }
#pragma unroll
        for (int off = 1; off < 16; off <<= 1)
#pragma unroll
            for (int r = 0; r < 4; ++r) p[r] += __shfl_xor(p[r], off);
        if (r16 == 0) {
            float fb = fcb[br];
#pragma unroll
            for (int r = 0; r < 4; ++r) {
                int e = w * 16 + q * 4 + r;
                yws[(size_t)br * 32768 + (size_t)b * 4096 + m * 64 + e] =
                    fmaxf(p[r] + fb, 0.f);
            }
        }
    }
}

__global__ __launch_bounds__(256) void k_mean(
    const float* __restrict__ yws, float* __restrict__ out)
{
    int idx = blockIdx.x * 256 + threadIdx.x;
    out[idx] = 0.5f * (yws[idx] + yws[32768 + idx]);
}

extern "C" void kernel_launch(void* const* d_in, const int* in_sizes, int n_in,
                              void* d_out, int out_size, void* d_ws, size_t ws_size,
                              hipStream_t stream)
{
    const float* x   = (const float*)d_in[0];
    const float* G   = (const float*)d_in[1];
    const float* wih = (const float*)d_in[2];
    const float* whh = (const float*)d_in[3];
    const float* bih = (const float*)d_in[4];
    const float* bhh = (const float*)d_in[5];
    const float* W0  = (const float*)d_in[6];
    const float* b0  = (const float*)d_in[7];
    const float* W1  = (const float*)d_in[8];
    const float* b1  = (const float*)d_in[9];
    const float* fcW = (const float*)d_in[10];
    const float* fcb = (const float*)d_in[11];
    float* out = (float*)d_out;

    // ws layout (shorts unless noted). Total ~68.2 MB.
    short* Xhi   = (short*)d_ws;            // 4,194,304
    short* Xlo   = Xhi + 4194304;
    short* T1hi  = Xlo + 4194304;           // 12,582,912
    short* T1lo  = T1hi + 12582912;
    float* yws   = (float*)(T1lo + 12582912);  // 65,536 f32
    short* Wfhi  = (short*)(yws + 65536);   // 147,456
    short* Wflo  = Wfhi + 147456;
    short* Gfhi  = Wflo + 147456;           // 24,576
    short* Gflo  = Gfhi + 24576;
    short* Whfhi = Gflo + 24576;            // 32,768
    short* Whflo = Whfhi + 32768;
    short* Y1hi  = Xhi;                     // reuse (X dead after layer-1 k_t1)
    short* Y1lo  = Xlo;

    k_prep<<<800, 256, 0, stream>>>(G, W0, W1, whh,
                                    Wfhi, Wflo, Gfhi, Gflo, Whfhi, Whflo);
    k_lstm<<<dim3(2048, 2), 256, 0, stream>>>(x, Whfhi, Whflo, wih, bih, bhh,
                                              Xhi, Xlo);

    // layer 1
    k_t1<<<dim3(2, 24, 16), 256, 0, stream>>>(Xhi, Xlo, G, T1hi, T1lo);
    k_t2fc<<<dim3(64, 8, 2), 256, 0, stream>>>(T1hi, T1lo, Wfhi, Wflo,
                                               Gfhi, Gflo, b0, fcW, fcb,
                                               Y1hi, Y1lo, yws, 0);
    // layer 2
    k_t1<<<dim3(2, 24, 16), 256, 0, stream>>>(Y1hi, Y1lo, G, T1hi, T1lo);
    k_t2fc<<<dim3(64, 8, 2), 256, 0, stream>>>(T1hi, T1lo,
                                               Wfhi + 73728, Wflo + 73728,
                                               Gfhi, Gflo, b1, fcW, fcb,
                                               (short*)nullptr, (short*)nullptr,
                                               yws, 1);
    k_mean<<<128, 256, 0, stream>>>(yws, out);
}

// Round 17
// 206.529 us; speedup vs baseline: 1.1374x; 1.1374x over previous
//
#include <hip/hip_runtime.h>
#include <hip/hip_bf16.h>

// M=2 branches, K=3 diffusion, N=64, I=1, H=64, B=8, T=12

typedef __attribute__((ext_vector_type(8))) short short8;   // 8 bf16 (4 VGPRs)
typedef __attribute__((ext_vector_type(4))) float f32x4;    // 4 fp32

__device__ __forceinline__ short bf16_cvt(float f) {       // RNE, 1-2 ops
    __hip_bfloat16 h = __float2bfloat16(f);
    return __builtin_bit_cast(short, h);
}
__device__ __forceinline__ float bf16_tof(short s) {
    union { unsigned u; float f; } v; v.u = ((unsigned)s) << 16;
    return v.f;
}

// ---------------- prep: pack W, G^T, Whh into MFMA fragment order ----------
// Wf [layer][br][d][ht][kk][lane][8] : 147456/plane
// Gf [br][et][kk][lane][8]           : 24576/plane
// Whf[br][kt][gg][w][lane][8]        : 32768/plane  (B[k][gate] of WhhT)
__global__ __launch_bounds__(256) void k_prep(
    const float* __restrict__ G, const float* __restrict__ W0,
    const float* __restrict__ W1, const float* __restrict__ whh,
    short* __restrict__ Wfhi, short* __restrict__ Wflo,
    short* __restrict__ Gfhi, short* __restrict__ Gflo,
    short* __restrict__ Whfhi, short* __restrict__ Whflo)
{
    int idx = blockIdx.x * 256 + threadIdx.x;
    float v; short *dh, *dl; int didx;
    if (idx < 147456) {
        int j = idx & 7, lane = (idx >> 3) & 63, kk = (idx >> 9) % 6;
        int t2 = idx / 3072;
        int ht = t2 & 3; t2 >>= 2;
        int d = t2 % 3; t2 /= 3;
        int br = t2 & 1, layer = t2 >> 1;
        int k = kk * 32 + ((lane >> 4) << 3) + j;
        int o = k >> 6, l = k & 63, h = ht * 16 + (lane & 15);
        const float* Wp = layer ? W1 : W0;
        v = Wp[((size_t)br * 576 + (o * 3 + d) * 64 + l) * 64 + h];
        dh = Wfhi; dl = Wflo; didx = idx;
    } else if (idx < 172032) {
        int i2 = idx - 147456;
        int j = i2 & 7, lane = (i2 >> 3) & 63, kk = (i2 >> 9) % 6;
        int t2 = i2 / 3072;
        int et = t2 & 3, br = t2 >> 2;
        int k = kk * 32 + ((lane >> 4) << 3) + j;
        int d = k >> 6, c = k & 63, e = et * 16 + (lane & 15);
        v = G[(((size_t)br * 3 + d) * 64 + c) * 64 + e];
        dh = Gfhi; dl = Gflo; didx = i2;
    } else {
        int i3 = idx - 172032;
        int j = i3 & 7, lane = (i3 >> 3) & 63;
        int w = (i3 >> 9) & 3, gg = (i3 >> 11) & 3;
        int kt = (i3 >> 13) & 1, br = (i3 >> 14) & 1;
        int gate = gg * 64 + w * 16 + (lane & 15);
        int k = kt * 32 + ((lane >> 4) << 3) + j;
        v = whh[((size_t)br * 256 + gate) * 64 + k];
        dh = Whfhi; dl = Whflo; didx = i3;
    }
    short hi = bf16_cvt(v);
    dh[didx] = hi;
    dl[didx] = bf16_cvt(v - bf16_tof(hi));
}

// ---------------- LSTM v4.3 (reverted from v5): register weights both ------
// ---------------- planes, x prefetch, (256,3). f32 X output ----------------
// v5 (Bl streamed from L2) REGRESSED 97.7->113 us: per-step load latency in
// the barrier-locked MFMA critical path; 38% occupancy didn't cover it.
__global__ __launch_bounds__(256, 3) void k_lstm(
    const float* __restrict__ x, const short* __restrict__ Whfhi,
    const short* __restrict__ Whflo, const float* __restrict__ wih,
    const float* __restrict__ bih, const float* __restrict__ bhh,
    float* __restrict__ Xout)
{
    __shared__ short hbuf[2][2][16][64];   // [dbuf][plane][seq][hid^swz] 8 KB
    const int tid = threadIdx.x;
    const int lane = tid & 63;
    const int w = __builtin_amdgcn_readfirstlane(tid >> 6);   // gate slice 0..3
    const int q = lane >> 4, r16 = lane & 15;
    const int br = blockIdx.y;
    const int bx = blockIdx.x;
    const int dg = bx & 3, o = (bx >> 2) & 63, b = bx >> 8;

    // weight-stationary B fragments (hi/lo), statically indexed -> registers
    short8 Bh[2][4], Bl[2][4];
    {
        const short* wbh = Whfhi + (size_t)br * 16384;
        const short* wbl = Whflo + (size_t)br * 16384;
#pragma unroll
        for (int kt = 0; kt < 2; ++kt)
#pragma unroll
            for (int gg = 0; gg < 4; ++gg) {
                const int bidx = (((kt * 4 + gg) * 4 + w) * 64 + lane) * 8;
                Bh[kt][gg] = *(const short8*)(wbh + bidx);
                Bl[kt][gg] = *(const short8*)(wbl + bidx);
            }
    }

    float wihv[4], biasv[4];
#pragma unroll
    for (int gg = 0; gg < 4; ++gg) {
        const int gate = gg * 64 + w * 16 + r16;
        wihv[gg] = wih[br * 256 + gate];
        biasv[gg] = bih[br * 256 + gate] + bhh[br * 256 + gate];
    }

    float cst[4] = {0.f, 0.f, 0.f, 0.f};
    const float* xb = x + (size_t)b * 12 * 4096 + o * 64 + dg * 16;
    const size_t hob = ((size_t)(br * 8 + b) * 64 + o) * 4096 + dg * 1024;
    const int hid = w * 16 + r16;

    const float L2E = 1.442695041f, L2E2 = 2.885390082f;

    float4 nx = *(const float4*)(xb + q * 4);   // prefetch t=0

    for (int t = 0; t < 12; ++t) {
        float4 xv = nx;
        if (t < 11)   // issue next step's x early; hides under MFMA+acts
            nx = *(const float4*)(xb + (size_t)(t + 1) * 4096 + q * 4);
        float xm[4] = {xv.x, xv.y, xv.z, xv.w};
        f32x4 acc[4];   // [gg]
#pragma unroll
        for (int r = 0; r < 4; ++r)
#pragma unroll
            for (int gg = 0; gg < 4; ++gg)
                acc[gg][r] = fmaf(xm[r], wihv[gg], biasv[gg]);

        if (t > 0) {
            const short* hb0 = &hbuf[t & 1][0][0][0];
#pragma unroll
            for (int kt = 0; kt < 2; ++kt) {
                const int col = (kt * 32 + q * 8) ^ ((r16 & 7) << 3);
                short8 Ah = *(const short8*)&hb0[r16 * 64 + col];
                short8 Al = *(const short8*)&hb0[1024 + r16 * 64 + col];
#pragma unroll
                for (int gg = 0; gg < 4; ++gg) {
                    acc[gg] = __builtin_amdgcn_mfma_f32_16x16x32_bf16(
                        Ah, Bh[kt][gg], acc[gg], 0, 0, 0);
                    acc[gg] = __builtin_amdgcn_mfma_f32_16x16x32_bf16(
                        Ah, Bl[kt][gg], acc[gg], 0, 0, 0);
                    acc[gg] = __builtin_amdgcn_mfma_f32_16x16x32_bf16(
                        Al, Bh[kt][gg], acc[gg], 0, 0, 0);
                }
            }
        }
        // activations, torch order i,f,g,o. Fused products share one rcp.
        float hv_[4];
#pragma unroll
        for (int r = 0; r < 4; ++r) {
            float ei = __builtin_amdgcn_exp2f(acc[0][r] * -L2E);
            float Eg = __builtin_amdgcn_exp2f(acc[2][r] * L2E2);
            float ef = __builtin_amdgcn_exp2f(acc[1][r] * -L2E);
            float igt = (Eg - 1.f) *
                        __builtin_amdgcn_rcpf((1.f + ei) * (Eg + 1.f));
            float fg = __builtin_amdgcn_rcpf(1.f + ef);
            float c = fmaf(fg, cst[r], igt);
            cst[r] = c;
            float eo = __builtin_amdgcn_exp2f(acc[3][r] * -L2E);
            float Ec = __builtin_amdgcn_exp2f(c * L2E2);
            hv_[r] = (Ec - 1.f) *
                     __builtin_amdgcn_rcpf((1.f + eo) * (Ec + 1.f));
        }
        if (t == 11) {
            // f32 output (t1 reconstructs f32 anyway; same bytes as hi+lo)
#pragma unroll
            for (int r = 0; r < 4; ++r) {
                int seq = q * 4 + r;
                Xout[hob + seq * 64 + hid] = hv_[r];
            }
        } else {
            short* hw0 = &hbuf[(t + 1) & 1][0][0][0];
#pragma unroll
            for (int r = 0; r < 4; ++r) {
                int seq = q * 4 + r;
                int col = hid ^ ((seq & 7) << 3);
                short hi = bf16_cvt(hv_[r]);
                hw0[seq * 64 + col] = hi;
                hw0[1024 + seq * 64 + col] = bf16_cvt(hv_[r] - bf16_tof(hi));
            }
            __syncthreads();   // single barrier per step (dbuf)
        }
    }
}

// ---------------- T1 v4: f32 X input, float4 loads, 8 cl x 8 m per thread --
// T1[br][o][b][m][cl] = sum_n G[br][o][n][m] * X[br][b][n][cl]
// X is now f32: drops the 24 unpack-VALU/n of the hi/lo format (t1 was the
// only consumer and summed the planes immediately). 2 float4 X + 2 float4 G
// loads + 64 fma per n. Output T1 stays hi/lo (feeds t2fc's MFMA).
__global__ __launch_bounds__(256, 3) void k_t1(
    const float* __restrict__ X, const float* __restrict__ G,
    short* __restrict__ T1hi, short* __restrict__ T1lo)
{
    const int o = blockIdx.y >> 3, b = blockIdx.y & 7;
    const int br = blockIdx.z >> 3, m0 = (blockIdx.z & 7) * 8;
    const int cl0 = blockIdx.x * 2048 + threadIdx.x * 8;
    const size_t xb = (size_t)(br * 8 + b) * 262144 + cl0;
    const float* gp = G + (size_t)(br * 3 + o) * 4096 + m0;

    float acc[8][8];   // [mm][c]
#pragma unroll
    for (int mm = 0; mm < 8; ++mm)
#pragma unroll
        for (int c = 0; c < 8; ++c) acc[mm][c] = 0.f;

    float4 nx0 = *(const float4*)(X + xb);       // prefetch n=0
    float4 nx1 = *(const float4*)(X + xb + 4);

#pragma unroll 2
    for (int n = 0; n < 64; ++n) {
        float4 x0 = nx0, x1 = nx1;
        if (n < 63) {   // issue n+1's loads; latency hides under n's fma
            nx0 = *(const float4*)(X + xb + (size_t)(n + 1) * 4096);
            nx1 = *(const float4*)(X + xb + (size_t)(n + 1) * 4096 + 4);
        }
        float xf[8] = {x0.x, x0.y, x0.z, x0.w, x1.x, x1.y, x1.z, x1.w};
        float4 g0 = *(const float4*)(gp + n * 64);
        float4 g1 = *(const float4*)(gp + n * 64 + 4);
        float gv[8] = {g0.x, g0.y, g0.z, g0.w, g1.x, g1.y, g1.z, g1.w};
#pragma unroll
        for (int mm = 0; mm < 8; ++mm) {
            float g = gv[mm];
#pragma unroll
            for (int c = 0; c < 8; ++c)
                acc[mm][c] = fmaf(xf[c], g, acc[mm][c]);
        }
    }
    const size_t tb = ((size_t)(br * 3 + o) * 8 + b) * 262144 + cl0;
#pragma unroll
    for (int mm = 0; mm < 8; ++mm) {
        short8 h8, l8;
#pragma unroll
        for (int c = 0; c < 8; ++c) {
            float f = acc[mm][c];
            short hi = bf16_cvt(f);
            h8[c] = hi;
            l8[c] = bf16_cvt(f - bf16_tof(hi));
        }
        *(short8*)(T1hi + tb + (size_t)(m0 + mm) * 4096) = h8;
        *(short8*)(T1lo + tb + (size_t)(m0 + mm) * 4096) = l8;
    }
}

// ---------------- T2 + FC (MFMA), LDS-staged T1, wave-split W --------------
// Per (br,b,m): U[d][c][h] = sum_{o,l} T1[o][c][l] W[(o,d)l][h]   (phase 1)
//              out[e][h]  = bias[h] + sum_{d,c} G[d][c][e] U[d][c][h] (ph 2)
// U layout: round-8 72-pad. LDS 55296 B. Layer-1 output now plain f32.
__global__ __launch_bounds__(256, 3) void k_t2fc(
    const short* __restrict__ T1hi, const short* __restrict__ T1lo,
    const short* __restrict__ Wfhi, const short* __restrict__ Wflo,
    const short* __restrict__ Gfhi, const short* __restrict__ Gflo,
    const float* __restrict__ bias, const float* __restrict__ fcW,
    const float* __restrict__ fcb,
    float* __restrict__ Yout, float* __restrict__ yws, int last)
{
    // region reuse: stage T1 [6][4096] (24576 sh) -> U [2][3][64][72] (27648)
    __shared__ __align__(16) short lds[27648];
    const int tid = threadIdx.x, lane = tid & 63;
    const int r16 = lane & 15, q = lane >> 4;
    const int w = __builtin_amdgcn_readfirstlane(tid >> 6);
    const int m = blockIdx.x, b = blockIdx.y, br = blockIdx.z;

    // ---- stage T1 slice (3 o x 2 plane x 4096) into LDS, XOR-swizzled ----
    const size_t t1b = (((size_t)br * 24 + b) * 64 + m) * 4096;
#pragma unroll
    for (int it = 0; it < 12; ++it) {
        int flat = it * 2048 + tid * 8;
        int p2 = flat >> 12;            // o*2 + plane
        int li = flat & 4095;           // c*64 + l
        int c = li >> 6, l = li & 63;
        const short* src = ((p2 & 1) ? T1lo : T1hi) + t1b +
                           (size_t)(p2 >> 1) * 2097152 + li;
        int dst = p2 * 4096 + c * 64 + (l ^ ((c & 7) << 3));
        *(short8*)&lds[dst] = *(const short8*)src;
    }
    __syncthreads();

    // ---- phase 1: U = T1 @ W. Wave w owns combos {w*3..w*3+2} (d*4+ht),
    //      all 4 c-tiles. W-frag loads: 36/wave (no cross-wave redundancy).
    f32x4 acc1[3][4];   // [i][ct]
#pragma unroll
    for (int i = 0; i < 3; ++i)
#pragma unroll
        for (int ct = 0; ct < 4; ++ct)
#pragma unroll
            for (int r = 0; r < 4; ++r) acc1[i][ct][r] = 0.f;

#pragma unroll
    for (int kk = 0; kk < 6; ++kk) {
        const int o = kk >> 1;
        short8 Wh[3], Wl[3];
#pragma unroll
        for (int i = 0; i < 3; ++i) {
            const int combo = w * 3 + i;          // d*4 + ht
            const int d = combo >> 2, ht = combo & 3;
            const int widx = ((((br * 3 + d) * 4 + ht) * 6 + kk) << 9) + lane * 8;
            Wh[i] = *(const short8*)(Wfhi + widx);
            Wl[i] = *(const short8*)(Wflo + widx);
        }
        short8 Ah[4], Al[4];
#pragma unroll
        for (int ct = 0; ct < 4; ++ct) {
            const int c = ct * 16 + r16;
            const int lbase = ((kk & 1) * 32 + q * 8) ^ ((r16 & 7) << 3);
            Ah[ct] = *(const short8*)&lds[(o * 2 + 0) * 4096 + c * 64 + lbase];
            Al[ct] = *(const short8*)&lds[(o * 2 + 1) * 4096 + c * 64 + lbase];
        }
#pragma unroll
        for (int i = 0; i < 3; ++i)
#pragma unroll
            for (int ct = 0; ct < 4; ++ct) {
                acc1[i][ct] = __builtin_amdgcn_mfma_f32_16x16x32_bf16(
                    Ah[ct], Wh[i], acc1[i][ct], 0, 0, 0);
                acc1[i][ct] = __builtin_amdgcn_mfma_f32_16x16x32_bf16(
                    Ah[ct], Wl[i], acc1[i][ct], 0, 0, 0);
                acc1[i][ct] = __builtin_amdgcn_mfma_f32_16x16x32_bf16(
                    Al[ct], Wh[i], acc1[i][ct], 0, 0, 0);
            }
    }
    __syncthreads();   // T1-LDS reads done; region becomes U

    short* u0 = lds;
    short* u1 = lds + 13824;   // 3*64*72
#pragma unroll
    for (int i = 0; i < 3; ++i) {
        const int combo = w * 3 + i;
        const int d = combo >> 2, ht = combo & 3;
        const int h = ht * 16 + r16;
#pragma unroll
        for (int ct = 0; ct < 4; ++ct)
#pragma unroll
            for (int r = 0; r < 4; ++r) {
                float f = acc1[i][ct][r];
                int c = ct * 16 + q * 4 + r;
                int ui = (d * 64 + h) * 72 + c;
                short hi = bf16_cvt(f);
                u0[ui] = hi;
                u1[ui] = bf16_cvt(f - bf16_tof(hi));
            }
    }
    __syncthreads();

    // ---- phase 2: out = G^T @ U + bias (wave w owns e-tile w)
    f32x4 acc2[4];
#pragma unroll
    for (int ht = 0; ht < 4; ++ht) {
        float bb = bias[br * 64 + ht * 16 + r16];
#pragma unroll
        for (int r = 0; r < 4; ++r) acc2[ht][r] = bb;
    }
#pragma unroll
    for (int kk = 0; kk < 6; ++kk) {
        const int gi = (((br * 4 + w) * 6 + kk) << 9) + lane * 8;
        short8 A2h = *(const short8*)(Gfhi + gi);
        short8 A2l = *(const short8*)(Gflo + gi);
        const int d = kk >> 1, cb = (kk & 1) * 32 + q * 8;
#pragma unroll
        for (int ht = 0; ht < 4; ++ht) {
            const int bi = (d * 64 + ht * 16 + r16) * 72 + cb;
            short8 B2h = *(const short8*)(u0 + bi);
            short8 B2l = *(const short8*)(u1 + bi);
            acc2[ht] = __builtin_amdgcn_mfma_f32_16x16x32_bf16(
                A2h, B2h, acc2[ht], 0, 0, 0);
            acc2[ht] = __builtin_amdgcn_mfma_f32_16x16x32_bf16(
                A2h, B2l, acc2[ht], 0, 0, 0);
            acc2[ht] = __builtin_amdgcn_mfma_f32_16x16x32_bf16(
                A2l, B2h, acc2[ht], 0, 0, 0);
        }
    }

    if (!last) {
        __syncthreads();
        float* ldsO = (float*)lds;   // 16 KB
#pragma unroll
        for (int ht = 0; ht < 4; ++ht)
#pragma unroll
            for (int r = 0; r < 4; ++r)
                ldsO[(w * 16 + q * 4 + r) * 64 + ht * 16 + r16] = acc2[ht][r];
        __syncthreads();
        // f32 output (t1 layer-2 reconstructs f32 anyway)
        const size_t yb = ((size_t)(br * 8 + b) * 64 + m) * 4096;
        const int i0 = tid * 16;
#pragma unroll
        for (int k4 = 0; k4 < 4; ++k4)
            *(float4*)(Yout + yb + i0 + k4 * 4) =
                *(const float4*)(ldsO + i0 + k4 * 4);
    } else {
        float p[4];
#pragma unroll
        for (int r = 0; r < 4; ++r) {
            p[r] = 0.f;
#pragma unroll
            for (int ht = 0; ht < 4; ++ht)
                p[r] += acc2[ht][r] * fcW[br * 64 + ht * 16 + r16];
        }
#pragma unroll
        for (int off = 1; off < 16; off <<= 1)
#pragma unroll
            for (int r = 0; r < 4; ++r) p[r] += __shfl_xor(p[r], off);
        if (r16 == 0) {
            float fb = fcb[br];
#pragma unroll
            for (int r = 0; r < 4; ++r) {
                int e = w * 16 + q * 4 + r;
                yws[(size_t)br * 32768 + (size_t)b * 4096 + m * 64 + e] =
                    fmaxf(p[r] + fb, 0.f);
            }
        }
    }
}

__global__ __launch_bounds__(256) void k_mean(
    const float* __restrict__ yws, float* __restrict__ out)
{
    int idx = blockIdx.x * 256 + threadIdx.x;
    out[idx] = 0.5f * (yws[idx] + yws[32768 + idx]);
}

extern "C" void kernel_launch(void* const* d_in, const int* in_sizes, int n_in,
                              void* d_out, int out_size, void* d_ws, size_t ws_size,
                              hipStream_t stream)
{
    const float* x   = (const float*)d_in[0];
    const float* G   = (const float*)d_in[1];
    const float* wih = (const float*)d_in[2];
    const float* whh = (const float*)d_in[3];
    const float* bih = (const float*)d_in[4];
    const float* bhh = (const float*)d_in[5];
    const float* W0  = (const float*)d_in[6];
    const float* b0  = (const float*)d_in[7];
    const float* W1  = (const float*)d_in[8];
    const float* b1  = (const float*)d_in[9];
    const float* fcW = (const float*)d_in[10];
    const float* fcb = (const float*)d_in[11];
    float* out = (float*)d_out;

    // ws layout. X32/Y1 are f32 now (same bytes as the old hi+lo pair).
    float* X32  = (float*)d_ws;             // 4,194,304 f32 (16.8 MB)
    short* T1hi = (short*)(X32 + 4194304);  // 12,582,912 shorts
    short* T1lo = T1hi + 12582912;
    float* yws  = (float*)(T1lo + 12582912);   // 65,536 f32
    short* Wfhi = (short*)(yws + 65536);    // 147,456
    short* Wflo = Wfhi + 147456;
    short* Gfhi = Wflo + 147456;            // 24,576
    short* Gflo = Gfhi + 24576;
    short* Whfhi = Gflo + 24576;            // 32,768
    short* Whflo = Whfhi + 32768;
    float* Y1   = X32;                      // reuse (X dead after layer-1 t1)

    k_prep<<<800, 256, 0, stream>>>(G, W0, W1, whh,
                                    Wfhi, Wflo, Gfhi, Gflo, Whfhi, Whflo);
    k_lstm<<<dim3(2048, 2), 256, 0, stream>>>(x, Whfhi, Whflo, wih, bih, bhh,
                                              X32);

    // layer 1
    k_t1<<<dim3(2, 24, 16), 256, 0, stream>>>(X32, G, T1hi, T1lo);
    k_t2fc<<<dim3(64, 8, 2), 256, 0, stream>>>(T1hi, T1lo, Wfhi, Wflo,
                                               Gfhi, Gflo, b0, fcW, fcb,
                                               Y1, yws, 0);
    // layer 2
    k_t1<<<dim3(2, 24, 16), 256, 0, stream>>>(Y1, G, T1hi, T1lo);
    k_t2fc<<<dim3(64, 8, 2), 256, 0, stream>>>(T1hi, T1lo,
                                               Wfhi + 73728, Wflo + 73728,
                                               Gfhi, Gflo, b1, fcW, fcb,
                                               (float*)nullptr, yws, 1);
    k_mean<<<128, 256, 0, stream>>>(yws, out);
}